// Round 7
// baseline (180.512 us; speedup 1.0000x reference)
//
#include <hip/hip_runtime.h>
#include <hip/hip_bf16.h>

#define N1 8192
#define N2 8192
#define CDIM 128
#define HC 60
#define WC 80
#define HIMG 480
#define WIMG 640
#define NPIX (HC * WC)
#define INV_DENOM (1.0f / (8192.0f * 256.0f))

using bf16x8 = __attribute__((ext_vector_type(8))) short;
using f32x4  = __attribute__((ext_vector_type(4))) float;

__device__ __forceinline__ ushort f2bf(float f) {
    union { float f; unsigned u; } x; x.f = f;
    unsigned u = x.u;
    unsigned r = (u + 0x7FFFu + ((u >> 16) & 1u)) >> 16;
    return (ushort)r;
}
__device__ __forceinline__ float bf2f(unsigned bits) {
    union { unsigned u; float f; } x; x.u = bits << 16; return x.f;
}
__device__ __forceinline__ unsigned key2bits(unsigned k) {
    return k ^ ((k & 0x8000u) ? 0x8000u : 0xFFFFu);
}
__device__ __forceinline__ unsigned bits2key(unsigned h) {
    return h ^ ((h & 0x8000u) ? 0xFFFFu : 0x8000u);
}

// ---------- prep: cvt A, cvt B to bf16 ----------
__global__ void prep_kernel(const float* __restrict__ kp1d,
                            const float* __restrict__ kp2d,
                            ushort* __restrict__ Abf, ushort* __restrict__ Bbf) {
    const int n4 = N1 * CDIM / 4;        // 262144
    int i = blockIdx.x * blockDim.x + threadIdx.x;
    if (i < n4) {
        float4 v = ((const float4*)kp1d)[i];
        ushort4 o;
        o.x = f2bf(v.x); o.y = f2bf(v.y); o.z = f2bf(v.z); o.w = f2bf(v.w);
        ((ushort4*)Abf)[i] = o;
    } else if (i < 2 * n4) {
        int k = i - n4;
        float4 v = ((const float4*)kp2d)[k];
        ushort4 o;
        o.x = f2bf(v.x); o.y = f2bf(v.y); o.z = f2bf(v.z); o.w = f2bf(v.w);
        ((ushort4*)Bbf)[k] = o;
    }
}

// ---------- desc2 transpose with LDS tiling (R6: was a 64-lane 4B scatter) ----------
__global__ void tr_kernel(const float* __restrict__ desc2, float* __restrict__ d2T) {
    __shared__ float tile[32][33];
    const int tx = threadIdx.x, ty = threadIdx.y;      // 32 x 8
    const int p0 = blockIdx.x * 32;                    // pixel tile (4800/32=150)
    const int c0 = blockIdx.y * 32;                    // channel tile (128/32=4)
    #pragma unroll
    for (int k = 0; k < 4; k++) {
        int c = c0 + ty + k * 8;
        tile[ty + k * 8][tx] = desc2[(size_t)c * NPIX + p0 + tx];
    }
    __syncthreads();
    #pragma unroll
    for (int k = 0; k < 4; k++) {
        int p = p0 + ty + k * 8;
        d2T[(size_t)p * CDIM + c0 + tx] = tile[tx][ty + k * 8];
    }
}

// ---------- positive term (unchanged) ----------
__global__ void pos_kernel(const float* __restrict__ wkp1,
                           const float* __restrict__ kp1d,
                           const float* __restrict__ desc2T,
                           float* __restrict__ ploss) {
    const int i = blockIdx.x;
    const int c = threadIdx.x;            // 128 threads = 2 waves
    float y = wkp1[2 * i], x = wkp1[2 * i + 1];
    float py = fminf(fmaxf(y / (float)(HIMG - 1) * (float)(HC - 1), 0.0f), (float)(HC - 1));
    float px = fminf(fmaxf(x / (float)(WIMG - 1) * (float)(WC - 1), 0.0f), (float)(WC - 1));
    int y0 = min(max((int)floorf(py), 0), HC - 2);
    int x0 = min(max((int)floorf(px), 0), WC - 2);
    float wy = py - (float)y0;
    float wx = px - (float)x0;
    const int p00 = y0 * WC + x0;
    float v00 = desc2T[(size_t)p00 * CDIM + c];
    float v01 = desc2T[(size_t)(p00 + 1) * CDIM + c];
    float v10 = desc2T[(size_t)(p00 + WC) * CDIM + c];
    float v11 = desc2T[(size_t)(p00 + WC + 1) * CDIM + c];
    float v = v00 * (1.0f - wy) * (1.0f - wx) + v01 * (1.0f - wy) * wx
            + v10 * wy * (1.0f - wx) + v11 * wy * wx;
    float a = kp1d[(size_t)i * CDIM + c];
    float s2 = v * v, sav = a * v;
    #pragma unroll
    for (int off = 32; off >= 1; off >>= 1) {
        s2  += __shfl_down(s2, off);
        sav += __shfl_down(sav, off);
    }
    __shared__ float p2[2], pav[2];
    int wave = threadIdx.x >> 6, lane = threadIdx.x & 63;
    if (lane == 0) { p2[wave] = s2; pav[wave] = sav; }
    __syncthreads();
    if (threadIdx.x == 0) {
        float nrm = sqrtf(p2[0] + p2[1]);
        float pd = (pav[0] + pav[1]) / fmaxf(nrm, 1e-12f);
        float l = fmaxf(1.0f - pd, 0.0f) * (256.0f / 3.0f);
        ploss[i] = l * INV_DENOM;
    }
}

__device__ __forceinline__ void stage_B(const ushort* __restrict__ B, int nbase,
                                        ushort* __restrict__ sB, int t) {
    // B tile: 128 cols x 128 k (32 KB). 16B slots XOR-swizzled so that the
    // K-loop's 16-lane column-strided ds_read_b128 hits the 8-access minimum
    // (bank of a slot depends only on slot&7; s^(j&7) spreads 16 rows over
    // all 8 bank-groups; unswizzled = all lanes on one group).
    const uint4* Bg = (const uint4*)(B + (size_t)nbase * CDIM);
    #pragma unroll
    for (int i2 = 0; i2 < 8; i2++) {
        int idx = t + 256 * i2;          // 0..2047
        int j = idx >> 4, s = idx & 15;
        *(uint4*)(sB + (j * 16 + (s ^ (j & 7))) * 8) = Bg[idx];
    }
}

// ---------- masked GEMM + in-LDS per-row packed histogram (R6) ----------
// Accounting R0-R5: the value-granularity handoff (dots/codes written, then
// re-read + re-binned by an 8192-block select) is the hidden ~80us. R6 bins
// inside the gemm at block scope: 64 rows x 1024 cols per block (8 splits x
// 128 mtiles), B staged per 128-col tile (R3's fatal omission), A in regs,
// R5's branchless epilogue + ONE ds_add per value into a 64x192-bin
// ushort-packed hist (counts <= 1024: no carry; non-candidates -> per-lane
// dummy slot: no same-address serialization). Block writes a 64x392B record
// once: 33 MB replaces 64 MB codes write + 64 MB select re-read + 64M
// re-binning atomics. >32 values (~0.25%): exact fixed-point ssum/scnt.
__global__ __launch_bounds__(256, 2)
void gemm_kernel(const ushort* __restrict__ A, const ushort* __restrict__ B,
                 const float* __restrict__ wkp1, const float* __restrict__ kp2,
                 unsigned* __restrict__ parts) {
    __shared__ ushort sB[128 * 128];          // 32 KB swizzled B tile
    __shared__ unsigned shist[64 * 96];       // 24 KB packed ushort hist
    __shared__ unsigned dmy[64];
    __shared__ unsigned ssum[64], scnt[64];
    __shared__ float s_w[128];

    const int t = threadIdx.x;
    const int split = blockIdx.x;             // 0..7
    const int mtile = blockIdx.y;             // 0..127
    const int m0 = mtile * 64;

    for (int i = t; i < 64 * 96; i += 256) shist[i] = 0u;
    if (t < 64) { ssum[t] = 0u; scnt[t] = 0u; }
    if (t < 128) s_w[t] = wkp1[2 * m0 + t];

    const int lane = t & 63;
    const int wave = t >> 6;
    const int wm = wave & 1, wn = wave >> 1;
    const int lrow = lane & 15, quad = lane >> 4;

    // A fragments resident in registers for the whole block (32 VGPR)
    bf16x8 afr[4][2];
    #pragma unroll
    for (int kit = 0; kit < 4; kit++)
        #pragma unroll
        for (int mt = 0; mt < 2; mt++)
            afr[kit][mt] = *(const bf16x8*)(A
                + (size_t)(m0 + wm * 32 + mt * 16 + lrow) * CDIM + kit * 32 + quad * 8);

    const float thr = 2.0f * sqrtf(32.0f) + 0.1f;
    const float thr2 = thr * thr;

    stage_B(B, split * 1024, sB, t);
    __syncthreads();

    for (int it = 0; it < 8; it++) {
        const int nbase = split * 1024 + it * 128;

        f32x4 acc[2][4];
        #pragma unroll
        for (int i = 0; i < 2; i++)
            #pragma unroll
            for (int j = 0; j < 4; j++) acc[i][j] = (f32x4){0.f, 0.f, 0.f, 0.f};

        #pragma unroll
        for (int kit = 0; kit < 4; kit++) {
            bf16x8 bfr[4];
            #pragma unroll
            for (int nt = 0; nt < 4; nt++) {
                int j = wn * 64 + nt * 16 + lrow;
                int slot = (kit * 4 + quad) ^ (j & 7);
                bfr[nt] = *(const bf16x8*)(sB + (j * 16 + slot) * 8);
            }
            #pragma unroll
            for (int mt = 0; mt < 2; mt++)
                #pragma unroll
                for (int nt = 0; nt < 4; nt++)
                    acc[mt][nt] = __builtin_amdgcn_mfma_f32_16x16x32_bf16(
                        afr[kit][mt], bfr[nt], acc[mt][nt], 0, 0, 0);
        }

        float ky[4], kx[4];
        #pragma unroll
        for (int nt = 0; nt < 4; nt++) {
            int j = nbase + wn * 64 + nt * 16 + lrow;
            ky[nt] = kp2[2 * j]; kx[nt] = kp2[2 * j + 1];
        }

        #pragma unroll
        for (int mt = 0; mt < 2; mt++) {
            #pragma unroll
            for (int r = 0; r < 4; r++) {
                const int il = wm * 32 + mt * 16 + quad * 4 + r;   // local row
                const float wy = s_w[2 * il], wx = s_w[2 * il + 1];
                unsigned hbits[4]; bool hi4[4]; bool anyhi = false;
                #pragma unroll
                for (int nt = 0; nt < 4; nt++) {
                    float dy = wy - ky[nt], dx = wx - kx[nt];
                    float v = acc[mt][nt][r];
                    v = (dy * dy + dx * dx <= thr2) ? v - 5.0f : v;
                    unsigned h = (unsigned)f2bf(v);
                    hbits[nt] = h;
                    unsigned u = h - 0x4141u;
                    unsigned* p = (u < 0xC0u) ? &shist[il * 96 + (int)(u >> 1)]
                                              : &dmy[lane];
                    atomicAdd(p, 1u << ((u & 1u) * 16u));
                    bool ih = ((u - 0xC0u) < 0x3D80u);      // v > 32, positive
                    hi4[nt] = ih; anyhi |= ih;
                }
                if (__any(anyhi)) {                          // rare
                    #pragma unroll
                    for (int nt = 0; nt < 4; nt++)
                        if (hi4[nt]) {
                            atomicAdd(&ssum[il], (unsigned)(int)(bf2f(hbits[nt]) * 4.0f));
                            atomicAdd(&scnt[il], 1u);
                        }
                }
            }
        }
        __syncthreads();
        if (it < 7) {
            stage_B(B, nbase + 128, sB, t);
            __syncthreads();
        }
    }

    // write record: 64 rows x [96 packed hist | S4 | cnt] (stride 128 uints)
    const size_t blockbase = (size_t)(mtile * 8 + split) * 64 * 128;
    for (int i = t; i < 64 * 98; i += 256) {
        int row = i / 98;
        int w = i - row * 98;
        unsigned val = (w < 96) ? shist[row * 96 + w]
                                : (w == 96 ? ssum[row] : scnt[row]);
        parts[blockbase + (size_t)row * 128 + w] = val;
    }
}

// ---------- per-row top-256 hinge from merged records (R6) ----------
// One wave per row (2048 blocks). Merge 8 packed records (halves <= 8*1024:
// no carry), redistribute via LDS, then the proven suffix-scan /
// threshold-find / f64 per-bin sums (bit-identical to R5's ok-path). >32
// contribution = 0.25*S4 - 0.2*nhi, exact fixed point -> deterministic.
// Fallback (tot<256 | nhi>255; P~0) recomputes the row from Abf/Bbf.
__global__ __launch_bounds__(256)
void select_kernel(const unsigned* __restrict__ parts,
                   const ushort* __restrict__ A, const ushort* __restrict__ B,
                   const float* __restrict__ wkp1, const float* __restrict__ kp2,
                   float* __restrict__ rloss) {
    const int wave = threadIdx.x >> 6, l = threadIdx.x & 63;
    const int g = blockIdx.x * 4 + wave;          // global row
    const int mtile = g >> 6, rowin = g & 63;

    __shared__ unsigned merged_s[4][192];
    unsigned* merged = merged_s[wave];

    unsigned w0 = 0, w1 = 0, nhi = 0, S4 = 0;
    #pragma unroll
    for (int rg = 0; rg < 8; rg++) {
        const unsigned* rp = parts + ((size_t)(mtile * 8 + rg) * 64 + rowin) * 128;
        w0 += rp[l];
        if (l < 32) w1 += rp[64 + l];
        S4  += rp[96];
        nhi += rp[97];
    }
    merged[2 * l]     = w0 & 0xFFFFu;
    merged[2 * l + 1] = w0 >> 16;
    if (l < 32) {
        merged[128 + 2 * l] = w1 & 0xFFFFu;
        merged[129 + 2 * l] = w1 >> 16;
    }
    __syncthreads();     // all 4 waves reach this exactly once; none after

    unsigned c0 = merged[l], c1 = merged[64 + l], c2 = merged[128 + l];

    // inclusive suffix-scan across lanes for each 64-bin chunk
    unsigned s0i = c0, s1i = c1, s2i = c2;
    #pragma unroll
    for (int off = 1; off < 64; off <<= 1) {
        unsigned t0 = __shfl_down(s0i, off);
        unsigned t1 = __shfl_down(s1i, off);
        unsigned t2 = __shfl_down(s2i, off);
        if (l + off < 64) { s0i += t0; s1i += t1; s2i += t2; }
    }
    const unsigned T0 = __shfl(s0i, 0), T1 = __shfl(s1i, 0), T2 = __shfl(s2i, 0);
    const unsigned tot = nhi + T0 + T1 + T2;      // count of values > 12.0

    const unsigned Ce0 = nhi + T1 + T2 + (s0i - c0);
    const unsigned Ce1 = nhi + T2 + (s1i - c1);
    const unsigned Ce2 = nhi + (s2i - c2);

    const bool ok = (tot >= 256u) && (nhi <= 255u);

    const float thr = 2.0f * sqrtf(32.0f) + 0.1f;
    const float thr2 = thr * thr;

    unsigned ktb;            // bf16 bits of 256th-largest (attained)
    double s = 0.0;
    int cgt = 0;

    if (ok) {
        unsigned long long m0 = __ballot(Ce0 < 256u);
        unsigned long long m1 = __ballot(Ce1 < 256u);
        unsigned long long m2 = __ballot(Ce2 < 256u);
        int bmin; unsigned cg;
        if (m0) { int fl = __ffsll(m0) - 1; bmin = fl;       cg = __shfl(Ce0, fl); }
        else if (m1) { int fl = __ffsll(m1) - 1; bmin = 64 + fl;  cg = __shfl(Ce1, fl); }
        else { int fl = __ffsll(m2) - 1; bmin = 128 + fl; cg = __shfl(Ce2, fl); }
        ktb = 0x4141u + (unsigned)bmin;
        cgt = (int)cg;
        // per-bin hinge sums: cnt * (f32)(val - 0.2f), exact in f64
        if (l > bmin)       s += (double)c0 * (double)(bf2f(0x4141u + (unsigned)l) - 0.2f);
        if (64 + l > bmin)  s += (double)c1 * (double)(bf2f(0x4141u + 64u + (unsigned)l) - 0.2f);
        if (128 + l > bmin) s += (double)c2 * (double)(bf2f(0x4141u + 128u + (unsigned)l) - 0.2f);
        #pragma unroll
        for (int off = 32; off >= 1; off >>= 1) s += __shfl_down(s, off);
        // >32 values: all above threshold; exact fixed-point sum
        if (l == 0)
            s += 0.25 * (double)S4 - (double)0.2f * (double)nhi;
    } else {
        // ---- exact fallback: recompute the row's dots on the fly (never in
        // practice; >10-sigma events). Scalar-FMA recompute of the bf16 dots.
        int lo = -1, hi = 65535;
        while (hi - lo > 1) {
            unsigned midu = (unsigned)((lo + hi) >> 1);
            int c = 0;
            for (int cc = l; cc < N2; cc += 64) {
                const ushort* ar = A + (size_t)g * CDIM;
                const ushort* br = B + (size_t)cc * CDIM;
                float av = 0.f;
                for (int k = 0; k < CDIM; k++)
                    av = fmaf(bf2f(ar[k]), bf2f(br[k]), av);
                float dy = wkp1[2 * g] - kp2[2 * cc];
                float dx = wkp1[2 * g + 1] - kp2[2 * cc + 1];
                if (dy * dy + dx * dx <= thr2) av -= 5.0f;
                c += (int)(bits2key((unsigned)f2bf(av)) > midu);
            }
            #pragma unroll
            for (int off = 32; off >= 1; off >>= 1) c += __shfl_down(c, off);
            c = __shfl(c, 0);
            if (c >= 256) lo = (int)midu; else hi = (int)midu;
        }
        unsigned kt = (unsigned)hi;
        for (int cc = l; cc < N2; cc += 64) {
            const ushort* ar = A + (size_t)g * CDIM;
            const ushort* br = B + (size_t)cc * CDIM;
            float av = 0.f;
            for (int k = 0; k < CDIM; k++)
                av = fmaf(bf2f(ar[k]), bf2f(br[k]), av);
            float dy = wkp1[2 * g] - kp2[2 * cc];
            float dx = wkp1[2 * g + 1] - kp2[2 * cc + 1];
            if (dy * dy + dx * dx <= thr2) av -= 5.0f;
            unsigned h = (unsigned)f2bf(av);
            if (bits2key(h) > kt) {
                s += (double)fmaxf(bf2f(h) - 0.2f, 0.f);
                cgt++;
            }
        }
        ktb = key2bits(kt);
        #pragma unroll
        for (int off = 32; off >= 1; off >>= 1) {
            s += __shfl_down(s, off);
            cgt += __shfl_down(cgt, off);
        }
    }

    if (l == 0) {
        float vt = bf2f(ktb);
        double S = s + (double)(256 - cgt) * (double)fmaxf(vt - 0.2f, 0.0f);
        rloss[g] = (float)(S * (double)INV_DENOM);
    }
}

// ---------- final reduce: sum 2*N1 floats -> out[0] ----------
__global__ void reduce_kernel(const float* __restrict__ a, float* __restrict__ out) {
    const int t = threadIdx.x;
    float s = 0.f;
    for (int i = t; i < 2 * N1; i += 256) s += a[i];
    #pragma unroll
    for (int off = 32; off >= 1; off >>= 1) s += __shfl_down(s, off);
    __shared__ float ws[4];
    int wave = t >> 6, lane = t & 63;
    if (lane == 0) ws[wave] = s;
    __syncthreads();
    if (t == 0) out[0] = ws[0] + ws[1] + ws[2] + ws[3];
}

extern "C" void kernel_launch(void* const* d_in, const int* in_sizes, int n_in,
                              void* d_out, int out_size, void* d_ws, size_t ws_size,
                              hipStream_t stream) {
    const float* wkp1  = (const float*)d_in[1];
    const float* kp2   = (const float*)d_in[2];
    const float* kp1d  = (const float*)d_in[3];
    const float* kp2d  = (const float*)d_in[4];
    const float* desc2 = (const float*)d_in[5];
    float* out = (float*)d_out;

    ushort*   Abf   = (ushort*)d_ws;                        // 2 MB
    ushort*   Bbf   = Abf + (size_t)N1 * CDIM;              // 2 MB
    float*    loss  = (float*)(Bbf + (size_t)N2 * CDIM);    // 64 KB (pos | rows)
    float*    d2T   = loss + 2 * N1;                        // 2.4 MB
    unsigned* parts = (unsigned*)(d2T + (size_t)NPIX * CDIM); // 33.5 MB records

    int n4 = N1 * CDIM / 4;
    prep_kernel<<<(2 * n4) / 256, 256, 0, stream>>>(kp1d, kp2d, Abf, Bbf);

    tr_kernel<<<dim3(NPIX / 32, CDIM / 32), dim3(32, 8), 0, stream>>>(desc2, d2T);

    pos_kernel<<<N1, 128, 0, stream>>>(wkp1, kp1d, d2T, loss);

    dim3 grid(8, N1 / 64);              // 8 splits x 128 mtiles = 1024 blocks
    gemm_kernel<<<grid, 256, 0, stream>>>(Abf, Bbf, wkp1, kp2, parts);

    select_kernel<<<N1 / 4, 256, 0, stream>>>(parts, Abf, Bbf, wkp1, kp2,
                                              loss + N1);

    reduce_kernel<<<1, 256, 0, stream>>>(loss, out);
}